// Round 1
// baseline (694.103 us; speedup 1.0000x reference)
//
#include <hip/hip_runtime.h>
#include <hip/hip_bf16.h>

#define HW 4096
#define CC 256
#define NBATCH 8
#define EPSF 1e-6f

typedef __attribute__((ext_vector_type(8))) short short8;
typedef __attribute__((ext_vector_type(4))) float floatx4;

// monotone float <-> unsigned key (order-preserving for all finite floats)
__device__ __forceinline__ unsigned fkey(float f){
    unsigned u = __float_as_uint(f);
    return (u & 0x80000000u) ? ~u : (u | 0x80000000u);
}
__device__ __forceinline__ float fdec(unsigned k){
    unsigned u = (k & 0x80000000u) ? (k ^ 0x80000000u) : ~k;
    return __uint_as_float(u);
}
__device__ __forceinline__ unsigned short f2bf(float f){
    unsigned u = __float_as_uint(f);
    u += 0x7FFFu + ((u >> 16) & 1);   // RNE to bf16
    return (unsigned short)(u >> 16);
}

// ---------------- kernel 1: per-channel mean of y ----------------
__global__ __launch_bounds__(256) void kmean(const float* __restrict__ y,
                                             float* __restrict__ ymu){
    const int c = blockIdx.x;
    const int t = threadIdx.x;
    float s = 0.f;
    for(int n = 0; n < NBATCH; n++){
        const float* p = y + ((size_t)n*CC + c)*HW;
        for(int i = t; i < HW; i += 256) s += p[i];
    }
    __shared__ float red[256];
    red[t] = s; __syncthreads();
    for(int off = 128; off > 0; off >>= 1){
        if(t < off) red[t] += red[t+off];
        __syncthreads();
    }
    if(t == 0) ymu[c] = red[0] * (1.0f/((float)NBATCH*HW));
}

// ------- kernel 2: center, L2-normalize over C, write [n][hw][c] bf16 -------
#define TROW 258
__global__ __launch_bounds__(256) void knorm(const float* __restrict__ x,
                                             const float* __restrict__ y,
                                             const float* __restrict__ ymu,
                                             __hip_bfloat16* __restrict__ xnT,
                                             __hip_bfloat16* __restrict__ ynT){
    __shared__ __align__(16) unsigned short tile[64*TROW];
    __shared__ float invn[64];
    __shared__ float partial[4][64];
    __shared__ float smu[CC];
    const int t   = threadIdx.x;
    const int hw0 = blockIdx.x * 64;
    const int n   = blockIdx.y;
    for(int c = t; c < CC; c += 256) smu[c] = ymu[c];
    const int hwl = t & 63;
    const int cch = t >> 6;
    for(int which = 0; which < 2; which++){
        const float* __restrict__ src = which ? y : x;
        __hip_bfloat16* __restrict__ dst = which ? ynT : xnT;
        __syncthreads();
        float ss = 0.f;
        for(int cc = 0; cc < 64; cc++){
            int c = cch*64 + cc;
            float v = src[((size_t)n*CC + c)*HW + hw0 + hwl] - smu[c];
            ss += v*v;
            tile[hwl*TROW + c] = f2bf(v);
        }
        partial[cch][hwl] = ss;
        __syncthreads();
        if(t < 64){
            float s = partial[0][t]+partial[1][t]+partial[2][t]+partial[3][t];
            invn[t] = rsqrtf(s);
        }
        __syncthreads();
        const int r  = t >> 2;
        const int qq = t & 3;
        float inv = invn[r];
        size_t gbase = ((size_t)n*HW + hw0 + r)*CC + qq*64;
        unsigned short* gdst = reinterpret_cast<unsigned short*>(dst);
        #pragma unroll
        for(int e = 0; e < 8; e++){
            const unsigned* lp = reinterpret_cast<const unsigned*>(&tile[r*TROW + qq*64 + e*8]);
            unsigned o[4];
            #pragma unroll
            for(int w2 = 0; w2 < 4; w2++){
                unsigned uu = lp[w2];
                float f0 = __uint_as_float((uu & 0xFFFFu) << 16) * inv;
                float f1 = __uint_as_float(uu & 0xFFFF0000u) * inv;
                o[w2] = (unsigned)f2bf(f0) | ((unsigned)f2bf(f1) << 16);
            }
            uint4 ov; ov.x=o[0]; ov.y=o[1]; ov.z=o[2]; ov.w=o[3];
            *reinterpret_cast<uint4*>(gdst + gbase + e*8) = ov;
        }
    }
}

// ---------------- kernel 3: init reduction buffers ----------------
__global__ __launch_bounds__(256) void kinit(unsigned* __restrict__ dmink,
                                             float* __restrict__ rowsum,
                                             unsigned* __restrict__ colmaxk){
    int i = blockIdx.x*256 + threadIdx.x;
    if(i < NBATCH*HW){
        dmink[i]   = 0xFFFFFFFFu;  // key for +inf-min
        rowsum[i]  = 0.f;
        colmaxk[i] = 0u;           // key below any positive float
    }
}

// ---------------- GEMM passes: MODE 0=rowmin(d) 1=rowsum(w) 2=colmax(ccx) ---
template<int MODE>
__global__ __launch_bounds__(256) void kgemm(
        const __hip_bfloat16* __restrict__ xnT,
        const __hip_bfloat16* __restrict__ ynT,
        unsigned* __restrict__ dmink,
        float* __restrict__ rowsum,
        unsigned* __restrict__ colmaxk){
    constexpr int LROW = 40;   // 32 k + 8 pad bf16 -> 80B rows, 16B aligned
    __shared__ __align__(16) unsigned short As[64*LROW];
    __shared__ __align__(16) unsigned short Bs[64*LROW];
    __shared__ unsigned statU[64];
    __shared__ float    statF[64];
    const int t  = threadIdx.x;
    const int j0 = blockIdx.x * 64;
    const int i0 = blockIdx.y * 64;
    const int n  = blockIdx.z;
    const unsigned short* Ab = reinterpret_cast<const unsigned short*>(xnT) + ((size_t)n*HW + i0)*CC;
    const unsigned short* Bb = reinterpret_cast<const unsigned short*>(ynT) + ((size_t)n*HW + j0)*CC;
    const int lrow = t >> 2;
    const int lk   = (t & 3) * 8;
    const int lane = t & 63;
    const int wave = t >> 6;
    const int q    = lane >> 4;
    const int l15  = lane & 15;
    const int wi   = wave >> 1;
    const int wj   = wave & 1;
    floatx4 acc[2][2];
    #pragma unroll
    for(int a = 0; a < 2; a++)
        #pragma unroll
        for(int b = 0; b < 2; b++)
            acc[a][b] = (floatx4){0.f,0.f,0.f,0.f};
    if(t < 64){ statU[t] = (MODE==2) ? 0u : 0xFFFFFFFFu; statF[t] = 0.f; }

    for(int kt = 0; kt < CC; kt += 32){
        __syncthreads();
        *reinterpret_cast<uint4*>(&As[lrow*LROW + lk]) =
            *reinterpret_cast<const uint4*>(Ab + (size_t)lrow*CC + kt + lk);
        *reinterpret_cast<uint4*>(&Bs[lrow*LROW + lk]) =
            *reinterpret_cast<const uint4*>(Bb + (size_t)lrow*CC + kt + lk);
        __syncthreads();
        short8 af[2], bfr[2];
        #pragma unroll
        for(int ti = 0; ti < 2; ti++)
            af[ti] = *reinterpret_cast<const short8*>(&As[(wi*32 + ti*16 + l15)*LROW + q*8]);
        #pragma unroll
        for(int tj = 0; tj < 2; tj++)
            bfr[tj] = *reinterpret_cast<const short8*>(&Bs[(wj*32 + tj*16 + l15)*LROW + q*8]);
        #pragma unroll
        for(int ti = 0; ti < 2; ti++)
            #pragma unroll
            for(int tj = 0; tj < 2; tj++)
                acc[ti][tj] = __builtin_amdgcn_mfma_f32_16x16x32_bf16(
                                  af[ti], bfr[tj], acc[ti][tj], 0, 0, 0);
    }

    // epilogue: D[q*4+r][l15] per 16x16 tile; row = wi*32+ti*16+q*4+r, col = wj*32+tj*16+l15
    if(MODE == 0){
        #pragma unroll
        for(int ti = 0; ti < 2; ti++)
            #pragma unroll
            for(int r = 0; r < 4; r++){
                float v = fminf(1.f - acc[ti][0][r], 1.f - acc[ti][1][r]);
                #pragma unroll
                for(int m = 1; m < 16; m <<= 1) v = fminf(v, __shfl_xor(v, m));
                if(l15 == 0) atomicMin(&statU[wi*32 + ti*16 + q*4 + r], fkey(v));
            }
        __syncthreads();
        if(t < 64) atomicMin(&dmink[(size_t)n*HW + i0 + t], statU[t]);
    } else if(MODE == 1){
        #pragma unroll
        for(int ti = 0; ti < 2; ti++)
            #pragma unroll
            for(int r = 0; r < 4; r++){
                int rl = wi*32 + ti*16 + q*4 + r;
                float dm = fdec(dmink[(size_t)n*HW + i0 + rl]);
                float sc = 2.f / (dm + EPSF);
                float v = __expf(2.f - (1.f - acc[ti][0][r]) * sc)
                        + __expf(2.f - (1.f - acc[ti][1][r]) * sc);
                #pragma unroll
                for(int m = 1; m < 16; m <<= 1) v += __shfl_xor(v, m);
                if(l15 == 0) atomicAdd(&statF[rl], v);
            }
        __syncthreads();
        if(t < 64) atomicAdd(&rowsum[(size_t)n*HW + i0 + t], statF[t]);
    } else {
        float sc[2][4], ri[2][4];
        #pragma unroll
        for(int ti = 0; ti < 2; ti++)
            #pragma unroll
            for(int r = 0; r < 4; r++){
                int rl = wi*32 + ti*16 + q*4 + r;
                size_t gi = (size_t)n*HW + i0 + rl;
                float dm = fdec(dmink[gi]);
                sc[ti][r] = 2.f / (dm + EPSF);
                ri[ti][r] = 1.f / rowsum[gi];
            }
        #pragma unroll
        for(int tj = 0; tj < 2; tj++){
            float v = 0.f;
            #pragma unroll
            for(int ti = 0; ti < 2; ti++)
                #pragma unroll
                for(int r = 0; r < 4; r++){
                    float w = __expf(2.f - (1.f - acc[ti][tj][r]) * sc[ti][r]);
                    v = fmaxf(v, w * ri[ti][r]);
                }
            v = fmaxf(v, __shfl_xor(v, 16));
            v = fmaxf(v, __shfl_xor(v, 32));
            if(q == 0) atomicMax(&statU[wj*32 + tj*16 + l15], fkey(v));
        }
        __syncthreads();
        if(t < 64) atomicMax(&colmaxk[(size_t)n*HW + j0 + t], statU[t]);
    }
}

// ---------------- final: loss = mean_n(-log(mean_j colmax + eps)) ----------
__global__ __launch_bounds__(256) void kfinal(const unsigned* __restrict__ colmaxk,
                                              float* __restrict__ out){
    __shared__ float red[256];
    const int t = threadIdx.x;
    float loss = 0.f;
    for(int n = 0; n < NBATCH; n++){
        float s = 0.f;
        for(int j = t; j < HW; j += 256) s += fdec(colmaxk[(size_t)n*HW + j]);
        red[t] = s; __syncthreads();
        for(int off = 128; off > 0; off >>= 1){
            if(t < off) red[t] += red[t+off];
            __syncthreads();
        }
        if(t == 0) loss += -logf(red[0]*(1.0f/HW) + EPSF);
        __syncthreads();
    }
    if(t == 0) out[0] = loss * (1.0f/NBATCH);
}

extern "C" void kernel_launch(void* const* d_in, const int* in_sizes, int n_in,
                              void* d_out, int out_size, void* d_ws, size_t ws_size,
                              hipStream_t stream){
    const float* x = (const float*)d_in[0];
    const float* y = (const float*)d_in[1];
    float* out = (float*)d_out;
    char* ws = (char*)d_ws;

    float* ymu = (float*)ws;
    size_t off = 1024;
    __hip_bfloat16* xnT = (__hip_bfloat16*)(ws + off); off += (size_t)NBATCH*HW*CC*2;
    __hip_bfloat16* ynT = (__hip_bfloat16*)(ws + off); off += (size_t)NBATCH*HW*CC*2;
    unsigned* dmink   = (unsigned*)(ws + off); off += (size_t)NBATCH*HW*4;
    float*    rowsum  = (float*)(ws + off);    off += (size_t)NBATCH*HW*4;
    unsigned* colmaxk = (unsigned*)(ws + off); off += (size_t)NBATCH*HW*4;

    kmean<<<dim3(CC), dim3(256), 0, stream>>>(y, ymu);
    knorm<<<dim3(HW/64, NBATCH), dim3(256), 0, stream>>>(x, y, ymu, xnT, ynT);
    kinit<<<dim3(NBATCH*HW/256), dim3(256), 0, stream>>>(dmink, rowsum, colmaxk);
    dim3 g(HW/64, HW/64, NBATCH);
    kgemm<0><<<g, dim3(256), 0, stream>>>(xnT, ynT, dmink, rowsum, colmaxk);
    kgemm<1><<<g, dim3(256), 0, stream>>>(xnT, ynT, dmink, rowsum, colmaxk);
    kgemm<2><<<g, dim3(256), 0, stream>>>(xnT, ynT, dmink, rowsum, colmaxk);
    kfinal<<<dim3(1), dim3(256), 0, stream>>>(colmaxk, out);
}

// Round 2
// 560.852 us; speedup vs baseline: 1.2376x; 1.2376x over previous
//
#include <hip/hip_runtime.h>
#include <hip/hip_bf16.h>
#include <hip/hip_fp16.h>

#define HW 4096
#define CC 256
#define NBATCH 8
#define EPSF 1e-6f

typedef __attribute__((ext_vector_type(8))) short short8;
typedef __attribute__((ext_vector_type(4))) float floatx4;
typedef unsigned short ushort_t;

// async global->LDS, 16B per lane
#define GLDS(g, l) __builtin_amdgcn_global_load_lds( \
    (const __attribute__((address_space(1))) void*)(const void*)(g), \
    (__attribute__((address_space(3))) void*)(void*)(l), 16, 0, 0)

// monotone float <-> unsigned key (order-preserving)
__device__ __forceinline__ unsigned fkey(float f){
    unsigned u = __float_as_uint(f);
    return (u & 0x80000000u) ? ~u : (u | 0x80000000u);
}
__device__ __forceinline__ float fdec(unsigned k){
    unsigned u = (k & 0x80000000u) ? (k ^ 0x80000000u) : ~k;
    return __uint_as_float(u);
}
__device__ __forceinline__ unsigned short f2bf(float f){
    unsigned u = __float_as_uint(f);
    u += 0x7FFFu + ((u >> 16) & 1);
    return (unsigned short)(u >> 16);
}
__device__ __forceinline__ unsigned short f2h(float f){
    return __half_as_ushort(__float2half(f));
}
__device__ __forceinline__ float h2f(unsigned short u){
    return __half2float(__ushort_as_half(u));
}

// ---------------- kernel 1: per-channel mean of y ----------------
__global__ __launch_bounds__(256) void kmean(const float* __restrict__ y,
                                             float* __restrict__ ymu){
    const int c = blockIdx.x;
    const int t = threadIdx.x;
    float s = 0.f;
    for(int n = 0; n < NBATCH; n++){
        const float* p = y + ((size_t)n*CC + c)*HW;
        for(int i = t; i < HW; i += 256) s += p[i];
    }
    __shared__ float red[256];
    red[t] = s; __syncthreads();
    for(int off = 128; off > 0; off >>= 1){
        if(t < off) red[t] += red[t+off];
        __syncthreads();
    }
    if(t == 0) ymu[c] = red[0] * (1.0f/((float)NBATCH*HW));
}

// ------- kernel 2: center, L2-normalize over C, write [n][hw][c] bf16 -------
#define TROW 258
__global__ __launch_bounds__(256) void knorm(const float* __restrict__ x,
                                             const float* __restrict__ y,
                                             const float* __restrict__ ymu,
                                             __hip_bfloat16* __restrict__ xnT,
                                             __hip_bfloat16* __restrict__ ynT){
    __shared__ __align__(16) unsigned short tile[64*TROW];
    __shared__ float invn[64];
    __shared__ float partial[4][64];
    __shared__ float smu[CC];
    const int t   = threadIdx.x;
    const int hw0 = blockIdx.x * 64;
    const int n   = blockIdx.y;
    for(int c = t; c < CC; c += 256) smu[c] = ymu[c];
    const int hwl = t & 63;
    const int cch = t >> 6;
    for(int which = 0; which < 2; which++){
        const float* __restrict__ src = which ? y : x;
        __hip_bfloat16* __restrict__ dst = which ? ynT : xnT;
        __syncthreads();
        float ss = 0.f;
        for(int cc = 0; cc < 64; cc++){
            int c = cch*64 + cc;
            float v = src[((size_t)n*CC + c)*HW + hw0 + hwl] - smu[c];
            ss += v*v;
            tile[hwl*TROW + c] = f2bf(v);
        }
        partial[cch][hwl] = ss;
        __syncthreads();
        if(t < 64){
            float s = partial[0][t]+partial[1][t]+partial[2][t]+partial[3][t];
            invn[t] = rsqrtf(s);
        }
        __syncthreads();
        const int r  = t >> 2;
        const int qq = t & 3;
        float inv = invn[r];
        size_t gbase = ((size_t)n*HW + hw0 + r)*CC + qq*64;
        unsigned short* gdst = reinterpret_cast<unsigned short*>(dst);
        #pragma unroll
        for(int e = 0; e < 8; e++){
            const unsigned* lp = reinterpret_cast<const unsigned*>(&tile[r*TROW + qq*64 + e*8]);
            unsigned o[4];
            #pragma unroll
            for(int w2 = 0; w2 < 4; w2++){
                unsigned uu = lp[w2];
                float f0 = __uint_as_float((uu & 0xFFFFu) << 16) * inv;
                float f1 = __uint_as_float(uu & 0xFFFF0000u) * inv;
                o[w2] = (unsigned)f2bf(f0) | ((unsigned)f2bf(f1) << 16);
            }
            uint4 ov; ov.x=o[0]; ov.y=o[1]; ov.z=o[2]; ov.w=o[3];
            *reinterpret_cast<uint4*>(gdst + gbase + e*8) = ov;
        }
    }
}

// ---------------- kernel 3: init reduction buffers ----------------
__global__ __launch_bounds__(256) void kinit(unsigned* __restrict__ dmink,
                                             float* __restrict__ rowsum,
                                             unsigned* __restrict__ colmaxk){
    int i = blockIdx.x*256 + threadIdx.x;
    if(i < NBATCH*HW){
        dmink[i]   = 0xFFFFFFFFu;
        rowsum[i]  = 0.f;
        colmaxk[i] = 0u;
    }
}

// ------------- 128x128 GEMM, m97-style. MODE: 0=rowmin 1=rowsum 2=colmax
// ------------- 3=rowmin + store S^T fp16 -------------
template<int MODE>
__global__ __launch_bounds__(256) void kgemm128(
        const __hip_bfloat16* __restrict__ xnT,
        const __hip_bfloat16* __restrict__ ynT,
        unsigned* __restrict__ dmink,
        float* __restrict__ rowsum,
        unsigned* __restrict__ colmaxk,
        unsigned short* __restrict__ ST){
    __shared__ __align__(16) unsigned short smem[9216]; // As 4096 | Bs 4096 ; T reuses [0..9216)
    __shared__ unsigned statU[128];
    __shared__ float    statF[128];
    unsigned short* As = smem;
    unsigned short* Bs = smem + 4096;

    const int t    = threadIdx.x;
    const int lane = t & 63;
    const int wave = t >> 6;
    const int q    = lane >> 4;
    const int l15  = lane & 15;
    const int wi   = wave >> 1;   // 0..1 : row half
    const int wj   = wave & 1;    // 0..1 : col half
    const int j0   = blockIdx.x * 128;
    const int i0   = blockIdx.y * 128;
    const int n    = blockIdx.z;
    const size_t nb = (size_t)n * HW;

    const unsigned short* Ab = reinterpret_cast<const unsigned short*>(xnT) + (nb + i0)*CC;
    const unsigned short* Bb = reinterpret_cast<const unsigned short*>(ynT) + (nb + j0)*CC;

    floatx4 acc[4][4];
    #pragma unroll
    for(int a = 0; a < 4; a++)
        #pragma unroll
        for(int b = 0; b < 4; b++)
            acc[a][b] = (floatx4){0.f,0.f,0.f,0.f};
    if(t < 128){ statU[t] = (MODE==2) ? 0u : 0xFFFFFFFFu; statF[t] = 0.f; }

    for(int kt = 0; kt < CC; kt += 32){
        __syncthreads();
        #pragma unroll
        for(int p = 0; p < 2; p++){
            int s = p*256 + t;               // granule id: row = s>>2, 16B chunk = s&3
            GLDS(Ab + (size_t)(s>>2)*CC + kt + (s&3)*8, &As[s*8]);
            GLDS(Bb + (size_t)(s>>2)*CC + kt + (s&3)*8, &Bs[s*8]);
        }
        __syncthreads();
        short8 af[4], bfr[4];
        #pragma unroll
        for(int ti = 0; ti < 4; ti++)
            af[ti] = *reinterpret_cast<const short8*>(&As[(wi*64 + ti*16 + l15)*32 + q*8]);
        #pragma unroll
        for(int tj = 0; tj < 4; tj++)
            bfr[tj] = *reinterpret_cast<const short8*>(&Bs[(wj*64 + tj*16 + l15)*32 + q*8]);
        #pragma unroll
        for(int ti = 0; ti < 4; ti++)
            #pragma unroll
            for(int tj = 0; tj < 4; tj++)
                acc[ti][tj] = __builtin_amdgcn_mfma_f32_16x16x32_bf16(
                                  af[ti], bfr[tj], acc[ti][tj], 0, 0, 0);
    }

    // C layout: D row = q*4+r, col = l15 per 16x16 tile.
    // global row = i0 + wi*64 + ti*16 + q*4 + r ; global col = j0 + wj*64 + tj*16 + l15
    if(MODE == 0 || MODE == 3){
        #pragma unroll
        for(int ti = 0; ti < 4; ti++)
            #pragma unroll
            for(int r = 0; r < 4; r++){
                float v = 1e30f;
                #pragma unroll
                for(int tj = 0; tj < 4; tj++)
                    v = fminf(v, 1.f - h2f(f2h(acc[ti][tj][r])));
                #pragma unroll
                for(int m = 1; m < 16; m <<= 1) v = fminf(v, __shfl_xor(v, m));
                if(l15 == 0) atomicMin(&statU[wi*64 + ti*16 + q*4 + r], fkey(v));
            }
        __syncthreads();
        if(t < 128) atomicMin(&dmink[nb + i0 + t], statU[t]);
    } else if(MODE == 1){
        #pragma unroll
        for(int ti = 0; ti < 4; ti++)
            #pragma unroll
            for(int r = 0; r < 4; r++){
                int rl = wi*64 + ti*16 + q*4 + r;
                float dm = fdec(dmink[nb + i0 + rl]);
                float sc = 2.f / (dm + EPSF);
                float c2 = 2.f - sc;
                float v = 0.f;
                #pragma unroll
                for(int tj = 0; tj < 4; tj++)
                    v += __expf(fmaf(h2f(f2h(acc[ti][tj][r])), sc, c2));
                #pragma unroll
                for(int m = 1; m < 16; m <<= 1) v += __shfl_xor(v, m);
                if(l15 == 0) atomicAdd(&statF[rl], v);
            }
        __syncthreads();
        if(t < 128) atomicAdd(&rowsum[nb + i0 + t], statF[t]);
    } else if(MODE == 2){
        float sc[4][4], bb[4][4];
        #pragma unroll
        for(int ti = 0; ti < 4; ti++)
            #pragma unroll
            for(int r = 0; r < 4; r++){
                size_t gi = nb + i0 + wi*64 + ti*16 + q*4 + r;
                float dm = fdec(dmink[gi]);
                float s_ = 2.f / (dm + EPSF);
                sc[ti][r] = s_;
                bb[ti][r] = 2.f - s_ - __logf(rowsum[gi]);
            }
        #pragma unroll
        for(int tj = 0; tj < 4; tj++){
            float v = 0.f;
            #pragma unroll
            for(int ti = 0; ti < 4; ti++)
                #pragma unroll
                for(int r = 0; r < 4; r++)
                    v = fmaxf(v, __expf(fmaf(h2f(f2h(acc[ti][tj][r])), sc[ti][r], bb[ti][r])));
            v = fmaxf(v, __shfl_xor(v, 16));
            v = fmaxf(v, __shfl_xor(v, 32));
            if(q == 0) atomicMax(&statU[wj*64 + tj*16 + l15], fkey(v));
        }
        __syncthreads();
        if(t < 128) atomicMax(&colmaxk[nb + j0 + t], statU[t]);
    }

    if(MODE == 3){
        // transpose-store S^T fp16 via LDS, two 64-row halves. T stride = 72 halves.
        unsigned short* Tb = smem;
        #pragma unroll
        for(int h = 0; h < 2; h++){
            if(h) __syncthreads();
            if(wi == h){
                #pragma unroll
                for(int ti = 0; ti < 4; ti++)
                    #pragma unroll
                    for(int tj = 0; tj < 4; tj++){
                        unsigned lo = (unsigned)f2h(acc[ti][tj][0]) | ((unsigned)f2h(acc[ti][tj][1]) << 16);
                        unsigned hi = (unsigned)f2h(acc[ti][tj][2]) | ((unsigned)f2h(acc[ti][tj][3]) << 16);
                        uint2 pv; pv.x = lo; pv.y = hi;
                        *reinterpret_cast<uint2*>(&Tb[(unsigned)(wj*64 + tj*16 + l15)*72 + ti*16 + q*4]) = pv;
                    }
            }
            __syncthreads();
            #pragma unroll
            for(int p = 0; p < 4; p++){
                int u  = p*256 + t;
                int jl = u >> 3;
                int c  = u & 7;
                uint4 v = *reinterpret_cast<const uint4*>(&Tb[jl*72 + c*8]);
                *reinterpret_cast<uint4*>(ST + (nb + j0 + jl)*(size_t)HW + i0 + h*64 + c*8) = v;
            }
        }
    }
}

// -------- fast-path pass 2: rowsum_i = sum_j exp(2-(1-s)*sc_i), S^T layout ----
__global__ __launch_bounds__(256) void krowsum(const unsigned short* __restrict__ ST,
                                               const unsigned* __restrict__ dmink,
                                               float* __restrict__ rowsum){
    const int t = threadIdx.x;
    const int n = blockIdx.z;
    const size_t nb = (size_t)n * HW;
    const int i8 = blockIdx.x*2048 + t*8;
    float sc[8], c2[8], sum[8];
    #pragma unroll
    for(int e = 0; e < 8; e++){
        float dm = fdec(dmink[nb + i8 + e]);
        sc[e] = 2.f / (dm + EPSF);
        c2[e] = 2.f - sc[e];
        sum[e] = 0.f;
    }
    const int jb = blockIdx.y*128;
    for(int j = jb; j < jb + 128; j++){
        uint4 u = *reinterpret_cast<const uint4*>(&ST[(nb + j)*(size_t)HW + i8]);
        unsigned uu[4] = {u.x, u.y, u.z, u.w};
        #pragma unroll
        for(int k = 0; k < 4; k++){
            sum[2*k]   += __expf(fmaf(h2f((unsigned short)(uu[k] & 0xFFFFu)), sc[2*k],   c2[2*k]));
            sum[2*k+1] += __expf(fmaf(h2f((unsigned short)(uu[k] >> 16)),     sc[2*k+1], c2[2*k+1]));
        }
    }
    #pragma unroll
    for(int e = 0; e < 8; e++) atomicAdd(&rowsum[nb + i8 + e], sum[e]);
}

// -------- fast-path pass 3: colmax_j = max_i exp(b_i + s*sc_i), S^T layout ----
__global__ __launch_bounds__(256) void kcolmax(const unsigned short* __restrict__ ST,
                                               const unsigned* __restrict__ dmink,
                                               const float* __restrict__ rowsum,
                                               unsigned* __restrict__ colmaxk){
    const int t    = threadIdx.x;
    const int lane = t & 63;
    const int wave = t >> 6;
    const int n    = blockIdx.z;
    const size_t nb = (size_t)n * HW;
    const int i8 = blockIdx.x*512 + lane*8;
    float sc[8], bb[8];
    #pragma unroll
    for(int e = 0; e < 8; e++){
        float dm = fdec(dmink[nb + i8 + e]);
        float s_ = 2.f / (dm + EPSF);
        sc[e] = s_;
        bb[e] = 2.f - s_ - __logf(rowsum[nb + i8 + e]);
    }
    const int jbase = blockIdx.y*256 + wave*64;
    for(int jj = 0; jj < 64; jj++){
        int j = jbase + jj;
        uint4 u = *reinterpret_cast<const uint4*>(&ST[(nb + j)*(size_t)HW + i8]);
        unsigned uu[4] = {u.x, u.y, u.z, u.w};
        float v = 0.f;
        #pragma unroll
        for(int k = 0; k < 4; k++){
            v = fmaxf(v, __expf(fmaf(h2f((unsigned short)(uu[k] & 0xFFFFu)), sc[2*k],   bb[2*k])));
            v = fmaxf(v, __expf(fmaf(h2f((unsigned short)(uu[k] >> 16)),     sc[2*k+1], bb[2*k+1])));
        }
        #pragma unroll
        for(int m = 1; m < 64; m <<= 1) v = fmaxf(v, __shfl_xor(v, m));
        if(lane == 0) atomicMax(&colmaxk[nb + j], fkey(v));
    }
}

// ---------------- final: loss = mean_n(-log(mean_j colmax + eps)) ----------
__global__ __launch_bounds__(256) void kfinal(const unsigned* __restrict__ colmaxk,
                                              float* __restrict__ out){
    __shared__ float red[256];
    const int t = threadIdx.x;
    float loss = 0.f;
    for(int n = 0; n < NBATCH; n++){
        float s = 0.f;
        for(int j = t; j < HW; j += 256) s += fdec(colmaxk[(size_t)n*HW + j]);
        red[t] = s; __syncthreads();
        for(int off = 128; off > 0; off >>= 1){
            if(t < off) red[t] += red[t+off];
            __syncthreads();
        }
        if(t == 0) loss += -logf(red[0]*(1.0f/HW) + EPSF);
        __syncthreads();
    }
    if(t == 0) out[0] = loss * (1.0f/NBATCH);
}

extern "C" void kernel_launch(void* const* d_in, const int* in_sizes, int n_in,
                              void* d_out, int out_size, void* d_ws, size_t ws_size,
                              hipStream_t stream){
    const float* x = (const float*)d_in[0];
    const float* y = (const float*)d_in[1];
    float* out = (float*)d_out;
    char* ws = (char*)d_ws;

    float* ymu = (float*)ws;
    size_t off = 1024;
    __hip_bfloat16* xnT = (__hip_bfloat16*)(ws + off); off += (size_t)NBATCH*HW*CC*2;
    __hip_bfloat16* ynT = (__hip_bfloat16*)(ws + off); off += (size_t)NBATCH*HW*CC*2;
    unsigned* dmink   = (unsigned*)(ws + off); off += (size_t)NBATCH*HW*4;
    float*    rowsum  = (float*)(ws + off);    off += (size_t)NBATCH*HW*4;
    unsigned* colmaxk = (unsigned*)(ws + off); off += (size_t)NBATCH*HW*4;
    unsigned short* ST = (unsigned short*)(ws + off);
    size_t need = off + (size_t)NBATCH*HW*(size_t)HW*2;
    const bool fast = (ws_size >= need);

    kmean<<<dim3(CC), dim3(256), 0, stream>>>(y, ymu);
    knorm<<<dim3(HW/64, NBATCH), dim3(256), 0, stream>>>(x, y, ymu, xnT, ynT);
    kinit<<<dim3(NBATCH*HW/256), dim3(256), 0, stream>>>(dmink, rowsum, colmaxk);
    dim3 g(HW/128, HW/128, NBATCH);
    if(fast){
        kgemm128<3><<<g, dim3(256), 0, stream>>>(xnT, ynT, dmink, rowsum, colmaxk, ST);
        krowsum<<<dim3(2, 32, NBATCH), dim3(256), 0, stream>>>(ST, dmink, rowsum);
        kcolmax<<<dim3(8, 16, NBATCH), dim3(256), 0, stream>>>(ST, dmink, rowsum, colmaxk);
    } else {
        kgemm128<0><<<g, dim3(256), 0, stream>>>(xnT, ynT, dmink, rowsum, colmaxk, ST);
        kgemm128<1><<<g, dim3(256), 0, stream>>>(xnT, ynT, dmink, rowsum, colmaxk, ST);
        kgemm128<2><<<g, dim3(256), 0, stream>>>(xnT, ynT, dmink, rowsum, colmaxk, ST);
    }
    kfinal<<<dim3(1), dim3(256), 0, stream>>>(colmaxk, out);
}

// Round 3
// 503.597 us; speedup vs baseline: 1.3783x; 1.1137x over previous
//
#include <hip/hip_runtime.h>
#include <hip/hip_bf16.h>

#define HW 4096
#define CC 256
#define NBATCH 8
#define EPSF 1e-6f

typedef __attribute__((ext_vector_type(8))) short short8;
typedef __attribute__((ext_vector_type(4))) float floatx4;

// monotone float <-> unsigned key (order-preserving)
__device__ __forceinline__ unsigned fkey(float f){
    unsigned u = __float_as_uint(f);
    return (u & 0x80000000u) ? ~u : (u | 0x80000000u);
}
__device__ __forceinline__ float fdec(unsigned k){
    unsigned u = (k & 0x80000000u) ? (k ^ 0x80000000u) : ~k;
    return __uint_as_float(u);
}
__device__ __forceinline__ unsigned short f2bf(float f){
    unsigned u = __float_as_uint(f);
    u += 0x7FFFu + ((u >> 16) & 1);
    return (unsigned short)(u >> 16);
}

// ---------------- kernel 1: per-channel mean of y ----------------
__global__ __launch_bounds__(256) void kmean(const float* __restrict__ y,
                                             float* __restrict__ ymu){
    const int c = blockIdx.x;
    const int t = threadIdx.x;
    float s = 0.f;
    for(int n = 0; n < NBATCH; n++){
        const float* p = y + ((size_t)n*CC + c)*HW;
        for(int i = t; i < HW; i += 256) s += p[i];
    }
    __shared__ float red[256];
    red[t] = s; __syncthreads();
    for(int off = 128; off > 0; off >>= 1){
        if(t < off) red[t] += red[t+off];
        __syncthreads();
    }
    if(t == 0) ymu[c] = red[0] * (1.0f/((float)NBATCH*HW));
}

// ---- kernel 2: center, normalize over C, emit MFMA-fragment-major bf16 ----
// layout per batch: elem(i, c) at  (i>>4)*4096 + kt*512 + q*128 + (i&15)*8 + e
//   where c = kt*32 + q*8 + e.  So a fragment load is base + lane*16B.
#define TROW 264
__global__ __launch_bounds__(256) void knorm(const float* __restrict__ x,
                                             const float* __restrict__ y,
                                             const float* __restrict__ ymu,
                                             unsigned short* __restrict__ xF,
                                             unsigned short* __restrict__ yF){
    __shared__ __align__(16) unsigned short tile[64*TROW];
    __shared__ float invn[64];
    __shared__ float partial[4][64];
    __shared__ float smu[CC];
    const int t   = threadIdx.x;
    const int hw0 = blockIdx.x * 64;
    const int n   = blockIdx.y;
    for(int c = t; c < CC; c += 256) smu[c] = ymu[c];
    const int hwl = t & 63;
    const int cch = t >> 6;
    for(int which = 0; which < 2; which++){
        const float* __restrict__ src = which ? y : x;
        unsigned short* __restrict__ dst = which ? yF : xF;
        __syncthreads();
        float ss = 0.f;
        for(int cc = 0; cc < 64; cc++){
            int c = cch*64 + cc;
            float v = src[((size_t)n*CC + c)*HW + hw0 + hwl] - smu[c];
            ss += v*v;
            tile[hwl*TROW + c] = f2bf(v);
        }
        partial[cch][hwl] = ss;
        __syncthreads();
        if(t < 64){
            float s = partial[0][t]+partial[1][t]+partial[2][t]+partial[3][t];
            invn[t] = rsqrtf(s);
        }
        __syncthreads();
        // write phase: fragment-major. block region = 4 it-groups = 16384 halves.
        size_t base = (size_t)n*HW*CC + (size_t)(hw0 >> 4)*4096;
        #pragma unroll
        for(int v8 = 0; v8 < 8; v8++){
            int g   = v8*256 + t;          // 0..2047, unit = 8 halves
            int lit = g >> 9;
            int kt  = (g >> 6) & 7;
            int qq  = (g >> 4) & 3;
            int ll  = g & 15;
            int hr  = lit*16 + ll;
            float inv = invn[hr];
            const unsigned* lp = reinterpret_cast<const unsigned*>(&tile[hr*TROW + kt*32 + qq*8]);
            unsigned o[4];
            #pragma unroll
            for(int w2 = 0; w2 < 4; w2++){
                unsigned uu = lp[w2];
                float f0 = __uint_as_float((uu & 0xFFFFu) << 16) * inv;
                float f1 = __uint_as_float(uu & 0xFFFF0000u) * inv;
                o[w2] = (unsigned)f2bf(f0) | ((unsigned)f2bf(f1) << 16);
            }
            uint4 ov; ov.x=o[0]; ov.y=o[1]; ov.z=o[2]; ov.w=o[3];
            *reinterpret_cast<uint4*>(dst + base + (size_t)g*8) = ov;
        }
    }
}

// ---------------- kernel 3: init colmax keys ----------------
__global__ __launch_bounds__(256) void kinit(unsigned* __restrict__ colmaxk){
    int i = blockIdx.x*256 + threadIdx.x;
    if(i < NBATCH*HW) colmaxk[i] = 0u;
}

// ---- fused 3-sweep kernel: block = 64-row i-panel, A in registers ----
__device__ __forceinline__ void sweep_acc(const unsigned short* __restrict__ Bp,
                                          const short8 af[4][8], floatx4 acc[4][4]){
    #pragma unroll
    for(int kt = 0; kt < 8; kt++){
        short8 b[4];
        #pragma unroll
        for(int tj = 0; tj < 4; tj++)
            b[tj] = *reinterpret_cast<const short8*>(Bp + tj*4096 + kt*512);
        #pragma unroll
        for(int ti = 0; ti < 4; ti++)
            #pragma unroll
            for(int tj = 0; tj < 4; tj++)
                acc[ti][tj] = __builtin_amdgcn_mfma_f32_16x16x32_bf16(
                                  af[ti][kt], b[tj], acc[ti][tj], 0, 0, 0);
    }
}

__global__ __launch_bounds__(256, 2) void kccx(const unsigned short* __restrict__ xF,
                                               const unsigned short* __restrict__ yF,
                                               unsigned* __restrict__ colmaxk){
    __shared__ unsigned dminU[64];
    __shared__ float    rsF[64];
    const int t    = threadIdx.x;
    const int lane = t & 63;
    const int wave = t >> 6;
    const int q    = lane >> 4;
    const int l15  = lane & 15;
    const int bid  = blockIdx.x;
    const int n    = bid & 7;          // batch <-> XCD affinity (L2 locality)
    const int ip   = bid >> 3;         // i-panel 0..63
    const size_t nbase = (size_t)n*HW*CC;
    const unsigned short* Ax = xF + nbase + (size_t)ip*16384;
    const unsigned short* Yn = yF + nbase + lane*8;
    if(t < 64){ dminU[t] = 0xFFFFFFFFu; rsF[t] = 0.f; }
    __syncthreads();

    short8 af[4][8];
    #pragma unroll
    for(int ti = 0; ti < 4; ti++)
        #pragma unroll
        for(int kt = 0; kt < 8; kt++)
            af[ti][kt] = *reinterpret_cast<const short8*>(Ax + ti*4096 + kt*512 + lane*8);

    // ---- sweep 1: d_min per row (block-local) ----
    float rmax[4][4];
    #pragma unroll
    for(int ti = 0; ti < 4; ti++)
        #pragma unroll
        for(int r = 0; r < 4; r++) rmax[ti][r] = -3e38f;
    #pragma unroll 1
    for(int js = 0; js < 16; js++){
        floatx4 acc[4][4];
        #pragma unroll
        for(int a = 0; a < 4; a++)
            #pragma unroll
            for(int b = 0; b < 4; b++) acc[a][b] = (floatx4){0.f,0.f,0.f,0.f};
        sweep_acc(Yn + (size_t)(js*16 + wave*4)*4096, af, acc);
        #pragma unroll
        for(int ti = 0; ti < 4; ti++)
            #pragma unroll
            for(int r = 0; r < 4; r++){
                float v = fmaxf(fmaxf(acc[ti][0][r], acc[ti][1][r]),
                                fmaxf(acc[ti][2][r], acc[ti][3][r]));
                v = fmaxf(v, __shfl_xor(v, 1));
                v = fmaxf(v, __shfl_xor(v, 2));
                v = fmaxf(v, __shfl_xor(v, 4));
                v = fmaxf(v, __shfl_xor(v, 8));
                rmax[ti][r] = fmaxf(rmax[ti][r], v);
            }
    }
    #pragma unroll
    for(int ti = 0; ti < 4; ti++)
        #pragma unroll
        for(int r = 0; r < 4; r++)
            if(l15 == 0) atomicMin(&dminU[ti*16 + q*4 + r], fkey(1.f - rmax[ti][r]));
    __syncthreads();
    float sc[4][4];
    #pragma unroll
    for(int ti = 0; ti < 4; ti++)
        #pragma unroll
        for(int r = 0; r < 4; r++)
            sc[ti][r] = 2.f / (fdec(dminU[ti*16 + q*4 + r]) + EPSF);

    // ---- sweep 2: rowsum of w (block-local) ----
    float rsum[4][4];
    #pragma unroll
    for(int ti = 0; ti < 4; ti++)
        #pragma unroll
        for(int r = 0; r < 4; r++) rsum[ti][r] = 0.f;
    #pragma unroll 1
    for(int js = 0; js < 16; js++){
        floatx4 acc[4][4];
        #pragma unroll
        for(int a = 0; a < 4; a++)
            #pragma unroll
            for(int b = 0; b < 4; b++) acc[a][b] = (floatx4){0.f,0.f,0.f,0.f};
        sweep_acc(Yn + (size_t)(js*16 + wave*4)*4096, af, acc);
        #pragma unroll
        for(int ti = 0; ti < 4; ti++)
            #pragma unroll
            for(int r = 0; r < 4; r++){
                float s_ = sc[ti][r];
                float c2 = 2.f - s_;
                float v = __expf(fmaf(acc[ti][0][r], s_, c2))
                        + __expf(fmaf(acc[ti][1][r], s_, c2))
                        + __expf(fmaf(acc[ti][2][r], s_, c2))
                        + __expf(fmaf(acc[ti][3][r], s_, c2));
                v += __shfl_xor(v, 1);
                v += __shfl_xor(v, 2);
                v += __shfl_xor(v, 4);
                v += __shfl_xor(v, 8);
                rsum[ti][r] += v;
            }
    }
    #pragma unroll
    for(int ti = 0; ti < 4; ti++)
        #pragma unroll
        for(int r = 0; r < 4; r++)
            if(l15 == 0) atomicAdd(&rsF[ti*16 + q*4 + r], rsum[ti][r]);
    __syncthreads();
    float bb[4][4];
    #pragma unroll
    for(int ti = 0; ti < 4; ti++)
        #pragma unroll
        for(int r = 0; r < 4; r++)
            bb[ti][r] = 2.f - sc[ti][r] - __logf(rsF[ti*16 + q*4 + r]);

    // ---- sweep 3: colmax of ccx (global atomics, batch-local words) ----
    #pragma unroll 1
    for(int js = 0; js < 16; js++){
        floatx4 acc[4][4];
        #pragma unroll
        for(int a = 0; a < 4; a++)
            #pragma unroll
            for(int b = 0; b < 4; b++) acc[a][b] = (floatx4){0.f,0.f,0.f,0.f};
        sweep_acc(Yn + (size_t)(js*16 + wave*4)*4096, af, acc);
        #pragma unroll
        for(int tj = 0; tj < 4; tj++){
            float v = 0.f;
            #pragma unroll
            for(int ti = 0; ti < 4; ti++)
                #pragma unroll
                for(int r = 0; r < 4; r++)
                    v = fmaxf(v, __expf(fmaf(acc[ti][tj][r], sc[ti][r], bb[ti][r])));
            v = fmaxf(v, __shfl_xor(v, 16));
            v = fmaxf(v, __shfl_xor(v, 32));
            if(lane < 16)
                atomicMax(&colmaxk[(size_t)n*HW + js*256 + wave*64 + tj*16 + lane], fkey(v));
        }
    }
}

// ---------------- final: loss = mean_n(-log(mean_j colmax + eps)) ----------
__global__ __launch_bounds__(256) void kfinal(const unsigned* __restrict__ colmaxk,
                                              float* __restrict__ out){
    __shared__ float red[256];
    const int t = threadIdx.x;
    float loss = 0.f;
    for(int n = 0; n < NBATCH; n++){
        float s = 0.f;
        for(int j = t; j < HW; j += 256) s += fdec(colmaxk[(size_t)n*HW + j]);
        red[t] = s; __syncthreads();
        for(int off = 128; off > 0; off >>= 1){
            if(t < off) red[t] += red[t+off];
            __syncthreads();
        }
        if(t == 0) loss += -logf(red[0]*(1.0f/HW) + EPSF);
        __syncthreads();
    }
    if(t == 0) out[0] = loss * (1.0f/NBATCH);
}

extern "C" void kernel_launch(void* const* d_in, const int* in_sizes, int n_in,
                              void* d_out, int out_size, void* d_ws, size_t ws_size,
                              hipStream_t stream){
    const float* x = (const float*)d_in[0];
    const float* y = (const float*)d_in[1];
    float* out = (float*)d_out;
    char* ws = (char*)d_ws;

    float* ymu = (float*)ws;
    size_t off = 1024;
    unsigned short* xF = (unsigned short*)(ws + off); off += (size_t)NBATCH*HW*CC*2;
    unsigned short* yF = (unsigned short*)(ws + off); off += (size_t)NBATCH*HW*CC*2;
    unsigned* colmaxk  = (unsigned*)(ws + off);       off += (size_t)NBATCH*HW*4;

    kmean<<<dim3(CC), dim3(256), 0, stream>>>(y, ymu);
    knorm<<<dim3(HW/64, NBATCH), dim3(256), 0, stream>>>(x, y, ymu, xF, yF);
    kinit<<<dim3(NBATCH*HW/256), dim3(256), 0, stream>>>(colmaxk);
    kccx<<<dim3(NBATCH*HW/64), dim3(256), 0, stream>>>(xF, yF, colmaxk);
    kfinal<<<dim3(1), dim3(256), 0, stream>>>(colmaxk, out);
}